// Round 1
// baseline (69.094 us; speedup 1.0000x reference)
//
#include <hip/hip_runtime.h>
#include <math.h>

#define DD 64          // feature dim (fixed by problem)
#define CPB 128        // chunks (blocks) per batch

__global__ void ha_init(float* ws, int count) {
    int i = blockIdx.x * blockDim.x + threadIdx.x;
    if (i < count) ws[i] = 0.0f;
}

__global__ __launch_bounds__(256) void ha_main(
    const float* __restrict__ key, const float* __restrict__ query,
    const float* __restrict__ value, const float* __restrict__ betap,
    const float* __restrict__ cp,
    float* __restrict__ wsU, float* __restrict__ wsS, float* __restrict__ wsD,
    int N)
{
    const int b     = blockIdx.x / CPB;
    const int chunk = blockIdx.x - b * CPB;
    const int npc   = (N + CPB - 1) / CPB;
    const int n0    = chunk * npc;
    const int nend  = min(n0 + npc, N);

    const int t = threadIdx.x;
    const int g = t >> 4;     // 16-lane group id within block (0..15)
    const int l = t & 15;     // lane within group -> owns dims 4l..4l+3

    const float beta = betap[0];
    const float cc   = cp[0];
    // dmax = 2*atanh(1-1e-5) = ln((2-1e-5)/1e-5); analytic softmax shift bound
    const float dmax = logf((2.0f - 1e-5f) / 1e-5f);
    const float mb   = fmaxf(beta * dmax, 0.0f) - cc;

    // query fragment for this lane + group-reduced ||q||^2
    const float4 q4 = reinterpret_cast<const float4*>(query)[b * (DD / 4) + l];
    float q2 = q4.x*q4.x + q4.y*q4.y + q4.z*q4.z + q4.w*q4.w;
    #pragma unroll
    for (int mk = 1; mk < 16; mk <<= 1) q2 += __shfl_xor(q2, mk, 64);

    const float4* __restrict__ key4 =
        reinterpret_cast<const float4*>(key) + (size_t)b * N * (DD / 4);
    const float4* __restrict__ val4 =
        reinterpret_cast<const float4*>(value) + (size_t)b * N * (DD / 4);

    float uX = 0.f, uY = 0.f, uZ = 0.f, uW = 0.f;  // sum e*lamb*v (4 dims/lane)
    float aS = 0.f;                                 // sum e
    float aD = 0.f;                                 // sum e*(lamb-1)

    for (int n = n0 + g; n < nend; n += 16) {
        const float4 k4 = key4[(size_t)n * (DD / 4) + l];
        const float4 v4 = val4[(size_t)n * (DD / 4) + l];
        float k2 = k4.x*k4.x + k4.y*k4.y + k4.z*k4.z + k4.w*k4.w;
        float kq = k4.x*q4.x + k4.y*q4.y + k4.z*q4.z + k4.w*q4.w;
        float v2 = v4.x*v4.x + v4.y*v4.y + v4.z*v4.z + v4.w*v4.w;
        #pragma unroll
        for (int mk = 1; mk < 16; mk <<= 1) {
            k2 += __shfl_xor(k2, mk, 64);
            kq += __shfl_xor(kq, mk, 64);
            v2 += __shfl_xor(v2, mk, 64);
        }
        // mobius_add(-k, q): ||num||^2 from scalars only
        const float A    = 1.0f - 2.0f * kq + q2;
        const float C    = 1.0f - k2;
        const float den  = fmaxf(1.0f - 2.0f * kq + k2 * q2, 1e-15f);
        const float num2 = fmaxf(A*A*k2 + C*C*q2 - 2.0f*A*C*kq, 0.0f);
        float r = sqrtf(num2) / den;
        r = fminf(r, 1.0f - 1e-5f);
        const float dist = logf((1.0f + r) / (1.0f - r));   // 2*atanh(r)
        const float e    = expf(beta * dist - cc - mb);
        const float lamb = 2.0f / fmaxf(1.0f - v2, 1e-10f);
        const float el   = e * lamb;
        uX += el * v4.x; uY += el * v4.y; uZ += el * v4.z; uW += el * v4.w;
        aS += e;
        aD += e * (lamb - 1.0f);
    }

    // reduce U across the 4 groups of the wave (lanes with equal (lane&15))
    #pragma unroll
    for (int mk = 16; mk < 64; mk <<= 1) {
        uX += __shfl_xor(uX, mk, 64);
        uY += __shfl_xor(uY, mk, 64);
        uZ += __shfl_xor(uZ, mk, 64);
        uW += __shfl_xor(uW, mk, 64);
    }
    // scalars: every lane of a group holds identical values -> full-wave sum
    // counts each n 16x; exact /16 later (power of two).
    #pragma unroll
    for (int mk = 1; mk < 64; mk <<= 1) {
        aS += __shfl_xor(aS, mk, 64);
        aD += __shfl_xor(aD, mk, 64);
    }

    __shared__ float ldsU[4][16][4];
    __shared__ float ldsS[4];
    __shared__ float ldsD[4];
    const int wave = t >> 6;
    const int lane = t & 63;
    if (lane < 16) {
        ldsU[wave][lane][0] = uX; ldsU[wave][lane][1] = uY;
        ldsU[wave][lane][2] = uZ; ldsU[wave][lane][3] = uW;
    }
    if (lane == 0) { ldsS[wave] = aS; ldsD[wave] = aD; }
    __syncthreads();
    if (t < 16) {
        #pragma unroll
        for (int j = 0; j < 4; ++j) {
            float s = ldsU[0][t][j] + ldsU[1][t][j] + ldsU[2][t][j] + ldsU[3][t][j];
            atomicAdd(&wsU[b * DD + t * 4 + j], s);
        }
    }
    if (t == 0) {
        atomicAdd(&wsS[b], (ldsS[0] + ldsS[1] + ldsS[2] + ldsS[3]) * 0.0625f);
        atomicAdd(&wsD[b], (ldsD[0] + ldsD[1] + ldsD[2] + ldsD[3]) * 0.0625f);
    }
}

__global__ void ha_final(const float* __restrict__ wsU, const float* __restrict__ wsS,
                         const float* __restrict__ wsD, float* __restrict__ out, int N)
{
    const int b = blockIdx.x;
    const int d = threadIdx.x;   // 64 threads = one wave
    const float S   = wsS[b];
    const float num = wsU[b * DD + d] / S;
    const float den = wsD[b] / S;
    const float tm  = num / fmaxf(den, 1e-10f);
    float n2 = tm * tm;
    #pragma unroll
    for (int mk = 1; mk < 64; mk <<= 1) n2 += __shfl_xor(n2, mk, 64);
    const float nn = sqrtf(n2);
    const float nc = fminf(fmaxf(nn, 1e-15f), 1.0f - 1e-5f);
    // tanh(0.5*atanh(nc)) == nc / (1 + sqrt(1 - nc^2))
    const float th  = nc / (1.0f + sqrtf(fmaxf(1.0f - nc * nc, 0.0f)));
    const float mid = th * (tm / fmaxf(nn, 1e-15f));
    out[b * DD + d] = (float)N * mid;
}

extern "C" void kernel_launch(void* const* d_in, const int* in_sizes, int n_in,
                              void* d_out, int out_size, void* d_ws, size_t ws_size,
                              hipStream_t stream) {
    const float* key   = (const float*)d_in[0];
    const float* query = (const float*)d_in[1];
    const float* value = (const float*)d_in[2];
    const float* beta  = (const float*)d_in[3];
    const float* c     = (const float*)d_in[4];
    float* out = (float*)d_out;

    const int BD = in_sizes[1];        // B*D
    const int B  = BD / DD;
    const int N  = in_sizes[0] / BD;   // 32768

    float* wsU = (float*)d_ws;         // B*DD accumulators: sum e*lamb*v
    float* wsS = wsU + B * DD;         // B: sum e
    float* wsD = wsS + B;              // B: sum e*(lamb-1)
    const int wcount = B * DD + 2 * B;

    ha_init<<<(wcount + 255) / 256, 256, 0, stream>>>((float*)d_ws, wcount);
    ha_main<<<B * CPB, 256, 0, stream>>>(key, query, value, beta, c,
                                         wsU, wsS, wsD, N);
    ha_final<<<B, DD, 0, stream>>>(wsU, wsS, wsD, out, N);
}

// Round 2
// 61.969 us; speedup vs baseline: 1.1150x; 1.1150x over previous
//
#include <hip/hip_runtime.h>
#include <math.h>

#define DD 64          // feature dim (fixed by problem)
#define CPB 64         // chunks (blocks) per batch

__global__ void ha_init(float* ws, int count) {
    int i = blockIdx.x * blockDim.x + threadIdx.x;
    if (i < count) ws[i] = 0.0f;
}

__device__ __forceinline__ float dot4(float4 a, float4 b) {
    return a.x*b.x + a.y*b.y + a.z*b.z + a.w*b.w;
}

__global__ __launch_bounds__(256) void ha_main(
    const float* __restrict__ key, const float* __restrict__ query,
    const float* __restrict__ value, const float* __restrict__ betap,
    const float* __restrict__ cp,
    float* __restrict__ wsU, float* __restrict__ wsS, float* __restrict__ wsD,
    int N)
{
    const int b     = blockIdx.x / CPB;
    const int chunk = blockIdx.x - b * CPB;
    const int npc   = (N + CPB - 1) / CPB;
    const int n0    = chunk * npc;
    const int nend  = min(n0 + npc, N);

    const int t    = threadIdx.x;
    const int wave = t >> 6;
    const int l    = t & 63;
    const int r    = l >> 2;   // row-group within wave (0..15)
    const int q    = l & 3;    // quad lane: owns float4 indices q, q+4, q+8, q+12

    const float beta = betap[0];
    const float cc   = cp[0];
    // analytic softmax shift: dist <= 2*atanh(1-1e-5)
    const float dmax = logf((2.0f - 1e-5f) / 1e-5f);
    const float mb   = fmaxf(beta * dmax, 0.0f) - cc;
    const float LOG2E = 1.4426950408889634f;
    // e = exp(beta*dist - cc - mb) = exp2(beta*log2(ratio) + s2)
    const float s2   = -(cc + mb) * LOG2E;

    // query fragment: this lane's quarter of the row (interleaved float4s)
    const float4* __restrict__ q4p = reinterpret_cast<const float4*>(query) + b * (DD / 4);
    float4 qv0 = q4p[q], qv1 = q4p[q + 4], qv2 = q4p[q + 8], qv3 = q4p[q + 12];
    float q2 = dot4(qv0,qv0) + dot4(qv1,qv1) + dot4(qv2,qv2) + dot4(qv3,qv3);
    q2 += __shfl_xor(q2, 1, 64);
    q2 += __shfl_xor(q2, 2, 64);

    const float4* __restrict__ key4 =
        reinterpret_cast<const float4*>(key) + (size_t)b * N * (DD / 4);
    const float4* __restrict__ val4 =
        reinterpret_cast<const float4*>(value) + (size_t)b * N * (DD / 4);

    float4 acc0 = {0,0,0,0}, acc1 = {0,0,0,0}, acc2 = {0,0,0,0}, acc3 = {0,0,0,0};
    float aS = 0.f, aD = 0.f;

    // wave processes 16 rows per iteration; quad-uniform loop bound
    for (int n = n0 + wave * 16 + r; n < nend; n += 64) {
        const size_t base = (size_t)n * (DD / 4) + q;
        const float4 k0 = key4[base],     k1 = key4[base + 4];
        const float4 k2v = key4[base + 8], k3 = key4[base + 12];
        const float4 v0 = val4[base],     v1 = val4[base + 4];
        const float4 v2v = val4[base + 8], v3 = val4[base + 12];

        float k2 = dot4(k0,k0) + dot4(k1,k1) + dot4(k2v,k2v) + dot4(k3,k3);
        float kq = dot4(k0,qv0) + dot4(k1,qv1) + dot4(k2v,qv2) + dot4(k3,qv3);
        float v2 = dot4(v0,v0) + dot4(v1,v1) + dot4(v2v,v2v) + dot4(v3,v3);
        k2 += __shfl_xor(k2, 1, 64); kq += __shfl_xor(kq, 1, 64); v2 += __shfl_xor(v2, 1, 64);
        k2 += __shfl_xor(k2, 2, 64); kq += __shfl_xor(kq, 2, 64); v2 += __shfl_xor(v2, 2, 64);

        // mobius_add(-k, q): ||num||^2 from scalars only
        const float A    = 1.0f - 2.0f * kq + q2;
        const float C    = 1.0f - k2;
        const float den  = fmaxf(1.0f - 2.0f * kq + k2 * q2, 1e-15f);
        const float num2 = fmaxf(A*A*k2 + C*C*q2 - 2.0f*A*C*kq, 0.0f);
        float rr = __builtin_amdgcn_sqrtf(num2) * __builtin_amdgcn_rcpf(den);
        rr = fminf(rr, 1.0f - 1e-5f);
        const float ratio = (1.0f + rr) * __builtin_amdgcn_rcpf(1.0f - rr);
        const float tl = __builtin_amdgcn_logf(ratio);          // log2(ratio)
        const float e  = __builtin_amdgcn_exp2f(fmaf(beta, tl, s2));
        const float lamb = 2.0f * __builtin_amdgcn_rcpf(fmaxf(1.0f - v2, 1e-10f));
        const float el = e * lamb;

        acc0.x += el*v0.x;  acc0.y += el*v0.y;  acc0.z += el*v0.z;  acc0.w += el*v0.w;
        acc1.x += el*v1.x;  acc1.y += el*v1.y;  acc1.z += el*v1.z;  acc1.w += el*v1.w;
        acc2.x += el*v2v.x; acc2.y += el*v2v.y; acc2.z += el*v2v.z; acc2.w += el*v2v.w;
        acc3.x += el*v3.x;  acc3.y += el*v3.y;  acc3.z += el*v3.z;  acc3.w += el*v3.w;
        aS += e;
        aD += e * (lamb - 1.0f);
    }

    // reduce U across the 16 quads of the wave (lanes with same q)
    #pragma unroll
    for (int mk = 4; mk < 64; mk <<= 1) {
        acc0.x += __shfl_xor(acc0.x, mk, 64); acc0.y += __shfl_xor(acc0.y, mk, 64);
        acc0.z += __shfl_xor(acc0.z, mk, 64); acc0.w += __shfl_xor(acc0.w, mk, 64);
        acc1.x += __shfl_xor(acc1.x, mk, 64); acc1.y += __shfl_xor(acc1.y, mk, 64);
        acc1.z += __shfl_xor(acc1.z, mk, 64); acc1.w += __shfl_xor(acc1.w, mk, 64);
        acc2.x += __shfl_xor(acc2.x, mk, 64); acc2.y += __shfl_xor(acc2.y, mk, 64);
        acc2.z += __shfl_xor(acc2.z, mk, 64); acc2.w += __shfl_xor(acc2.w, mk, 64);
        acc3.x += __shfl_xor(acc3.x, mk, 64); acc3.y += __shfl_xor(acc3.y, mk, 64);
        acc3.z += __shfl_xor(acc3.z, mk, 64); acc3.w += __shfl_xor(acc3.w, mk, 64);
    }
    // scalars: each row counted 4x (quad-redundant); full-wave sum then /4
    #pragma unroll
    for (int mk = 1; mk < 64; mk <<= 1) {
        aS += __shfl_xor(aS, mk, 64);
        aD += __shfl_xor(aD, mk, 64);
    }

    __shared__ float ldsU[4][4][16];   // [wave][q][f4idx*4+comp]
    __shared__ float ldsS[4];
    __shared__ float ldsD[4];
    if (l < 4) {
        ldsU[wave][l][0]  = acc0.x; ldsU[wave][l][1]  = acc0.y;
        ldsU[wave][l][2]  = acc0.z; ldsU[wave][l][3]  = acc0.w;
        ldsU[wave][l][4]  = acc1.x; ldsU[wave][l][5]  = acc1.y;
        ldsU[wave][l][6]  = acc1.z; ldsU[wave][l][7]  = acc1.w;
        ldsU[wave][l][8]  = acc2.x; ldsU[wave][l][9]  = acc2.y;
        ldsU[wave][l][10] = acc2.z; ldsU[wave][l][11] = acc2.w;
        ldsU[wave][l][12] = acc3.x; ldsU[wave][l][13] = acc3.y;
        ldsU[wave][l][14] = acc3.z; ldsU[wave][l][15] = acc3.w;
    }
    if (l == 0) { ldsS[wave] = aS; ldsD[wave] = aD; }
    __syncthreads();
    if (t < DD) {
        // dim d = t: float4 idx f = d>>2 = q + 4*j -> q=f&3, j=f>>2; comp c=d&3
        const int qq = (t >> 2) & 3;
        const int jj = t >> 4;
        const int c  = t & 3;
        const float s = ldsU[0][qq][jj*4 + c] + ldsU[1][qq][jj*4 + c]
                      + ldsU[2][qq][jj*4 + c] + ldsU[3][qq][jj*4 + c];
        atomicAdd(&wsU[b * DD + t], s);
    }
    if (t == 0) {
        atomicAdd(&wsS[b], (ldsS[0] + ldsS[1] + ldsS[2] + ldsS[3]) * 0.25f);
        atomicAdd(&wsD[b], (ldsD[0] + ldsD[1] + ldsD[2] + ldsD[3]) * 0.25f);
    }
}

__global__ void ha_final(const float* __restrict__ wsU, const float* __restrict__ wsS,
                         const float* __restrict__ wsD, float* __restrict__ out, int N)
{
    const int b = blockIdx.x;
    const int d = threadIdx.x;   // 64 threads = one wave
    const float S   = wsS[b];
    const float num = wsU[b * DD + d] / S;
    const float den = wsD[b] / S;
    const float tm  = num / fmaxf(den, 1e-10f);
    float n2 = tm * tm;
    #pragma unroll
    for (int mk = 1; mk < 64; mk <<= 1) n2 += __shfl_xor(n2, mk, 64);
    const float nn = sqrtf(n2);
    const float nc = fminf(fmaxf(nn, 1e-15f), 1.0f - 1e-5f);
    // tanh(0.5*atanh(nc)) == nc / (1 + sqrt(1 - nc^2))
    const float th  = nc / (1.0f + sqrtf(fmaxf(1.0f - nc * nc, 0.0f)));
    const float mid = th * (tm / fmaxf(nn, 1e-15f));
    out[b * DD + d] = (float)N * mid;
}

extern "C" void kernel_launch(void* const* d_in, const int* in_sizes, int n_in,
                              void* d_out, int out_size, void* d_ws, size_t ws_size,
                              hipStream_t stream) {
    const float* key   = (const float*)d_in[0];
    const float* query = (const float*)d_in[1];
    const float* value = (const float*)d_in[2];
    const float* beta  = (const float*)d_in[3];
    const float* c     = (const float*)d_in[4];
    float* out = (float*)d_out;

    const int BD = in_sizes[1];        // B*D
    const int B  = BD / DD;
    const int N  = in_sizes[0] / BD;   // 32768

    float* wsU = (float*)d_ws;         // B*DD accumulators: sum e*lamb*v
    float* wsS = wsU + B * DD;         // B: sum e
    float* wsD = wsS + B;              // B: sum e*(lamb-1)
    const int wcount = B * DD + 2 * B;

    ha_init<<<(wcount + 255) / 256, 256, 0, stream>>>((float*)d_ws, wcount);
    ha_main<<<B * CPB, 256, 0, stream>>>(key, query, value, beta, c,
                                         wsU, wsS, wsD, N);
    ha_final<<<B, DD, 0, stream>>>(wsU, wsS, wsD, out, N);
}